// Round 3
// baseline (346.524 us; speedup 1.0000x reference)
//
#include <hip/hip_runtime.h>
#include <hip/hip_bf16.h>
#include <hip/hip_fp16.h>

typedef __attribute__((ext_vector_type(8))) short short8;
typedef __attribute__((ext_vector_type(4))) float f32x4;

#define DEVI __device__ __forceinline__

DEVI unsigned short f2bf(float f){
  __hip_bfloat16 h = __float2bfloat16(f);
  unsigned short u; __builtin_memcpy(&u, &h, 2); return u;
}

// ---------------- cast fp32 -> bf16 ----------------
__global__ void cast_f32_bf16(const float* __restrict__ in, unsigned short* __restrict__ out, int n4){
  int stride = gridDim.x * blockDim.x;
  for (int i = blockIdx.x*blockDim.x + threadIdx.x; i < n4; i += stride){
    float4 f = reinterpret_cast<const float4*>(in)[i];
    ushort4 o;
    o.x = f2bf(f.x); o.y = f2bf(f.y); o.z = f2bf(f.z); o.w = f2bf(f.w);
    reinterpret_cast<ushort4*>(out)[i] = o;
  }
}

// ---------------- transpose + cast: WT[n][k] = W[k][n] ----------------
__global__ void transpose_cast_w(const float* __restrict__ W, unsigned short* __restrict__ WT, int K, int N){
  __shared__ float tile[32][33];
  int bn = blockIdx.x*32, bk = blockIdx.y*32;
  int tx = threadIdx.x & 31, ty = threadIdx.x >> 5;
  for (int r=0;r<32;r+=8)
    tile[ty+r][tx] = W[(long)(bk+ty+r)*N + bn+tx];
  __syncthreads();
  for (int r=0;r<32;r+=8)
    WT[(long)(bn+ty+r)*K + bk+tx] = (short)f2bf(tile[tx][ty+r]);
}

// ---------------- async global->LDS, 16B/lane ----------------
DEVI void stage16(const short* gsrc, short* lbase){
  __builtin_amdgcn_global_load_lds(
      (const __attribute__((address_space(1))) unsigned int*)gsrc,
      (__attribute__((address_space(3))) unsigned int*)lbase, 16, 0, 0);
}

// Stage one 16KB K-half block (256 rows x 32 kelems) with precomputed offsets.
DEVI void stage2(const short* base, long o0, long o1, short* blk, int w){
  stage16(base + o0, blk + w*512);
  stage16(base + o1, blk + (8+w)*512);
}

// ---------------- 256x256 8-phase GEMM: C = scale*(A @ Bt^T) + bias ----------
// OT: 0=f32, 1=f16, 2=bf16.  BIAS: 0 none, 1 per-col, 2 per-row.
// BK=64 (2 K-halves), 512 thr = 8 waves (2M x 4N), dbuf LDS 128KB.
// LDS block idx = buf*4 + op*2 + khalf (op 0=A,1=B), 8192 shorts (16KB) each.
// K-loop barriers are inline-asm s_barrier (no compiler vmcnt drain); counted
// vmcnt(4) only at phases 4 and 8, each immediately BEFORE its barrier so all
// waves' covered loads are landed after the sync.
template<int OT, int BIAS>
__global__ __launch_bounds__(512, 2)
void gemm8(const short* __restrict__ A, const short* __restrict__ Bt,
           const float* __restrict__ bias, void* __restrict__ Cv,
           int N, int K, long sA, long sB, long sC, float scale, int nx, int ny)
{
  extern __shared__ short lds[];
  // bijective XCD swizzle (all launches have nwg % 8 == 0)
  const int nwg = gridDim.x;
  const int cpx = nwg >> 3;
  const int wg  = (blockIdx.x & 7)*cpx + (blockIdx.x >> 3);
  const int bx  = wg % nx;
  const int tmp = wg / nx;
  const int by  = tmp % ny;
  const long bz = tmp / ny;
  const int m0 = bx * 256, n0 = by * 256;
  const short* Ab = A  + bz*sA + (long)m0 * K;
  const short* Bb = Bt + bz*sB + (long)n0 * K;

  const int t = threadIdx.x, lane = t & 63, w = t >> 6;
  const int wr = w >> 2, wc = w & 3;            // 2M x 4N wave grid

  // staging invariants: chunk rows + pre-swizzled k (st_16x32 involution)
  const int rr = lane >> 2;
  const int kk = ((lane & 3) * 8) ^ ((lane & 32) ? 16 : 0);
  const long off0 = (long)(( w     )*16 + rr) * K + kk;
  const long off1 = (long)(( 8 + w )*16 + rr) * K + kk;

  // ds_read invariants: swizzled per-lane byte offset within each 1KB subtile
  const int la = lane & 15;
  const int lsw = (la*64 + ((lane>>4)<<4)) ^ ((la>=8)?32:0);
  const short* AP = lds + (lsw>>1) + wr*4096;           // + rowblk*512 per frag
  const short* BP = lds + (lsw>>1) + 16384 + wc*2048;   // B blocks start at blk2

  f32x4 acc[8][4] = {};
  short8 bv[4];

  const int NT = K >> 6;          // K-tiles of 64
  const int niter = NT >> 1;      // 2 K-tiles per iteration

  // ---- prologue: tile0 -> buf0 (A.k0,B.k0,A.k1,B.k1), tile1 k0 -> buf1 ----
  stage2(Ab,      off0, off1, lds + 0,     w);
  stage2(Bb,      off0, off1, lds + 16384, w);
  stage2(Ab + 32, off0, off1, lds + 8192,  w);
  stage2(Bb + 32, off0, off1, lds + 24576, w);
  stage2(Ab + 64, off0, off1, lds + 32768, w);
  stage2(Bb + 64, off0, off1, lds + 49152, w);
  asm volatile("s_waitcnt vmcnt(4)" ::: "memory");   // buf0 fully landed
  asm volatile("s_barrier" ::: "memory");

#define PH(CBUF, QM, QK, SBASE, SOFF, SBLK, TAILVM) do {                        \
    const short* ap_ = AP + (CBUF)*32768 + (QK)*8192 + (QM)*2048;               \
    short8 a0_ = *reinterpret_cast<const short8*>(ap_ + 0*512);                 \
    short8 a1_ = *reinterpret_cast<const short8*>(ap_ + 1*512);                 \
    short8 a2_ = *reinterpret_cast<const short8*>(ap_ + 2*512);                 \
    short8 a3_ = *reinterpret_cast<const short8*>(ap_ + 3*512);                 \
    if ((QM) == 0){                                                             \
      const short* bp_ = BP + (CBUF)*32768 + (QK)*8192;                         \
      bv[0] = *reinterpret_cast<const short8*>(bp_ + 0*512);                    \
      bv[1] = *reinterpret_cast<const short8*>(bp_ + 1*512);                    \
      bv[2] = *reinterpret_cast<const short8*>(bp_ + 2*512);                    \
      bv[3] = *reinterpret_cast<const short8*>(bp_ + 3*512);                    \
    }                                                                           \
    stage2((SBASE) + (SOFF), off0, off1, lds + (SBLK), w);                      \
    asm volatile("s_barrier" ::: "memory");                                     \
    asm volatile("s_waitcnt lgkmcnt(0)" ::: "memory");                          \
    __builtin_amdgcn_s_setprio(1);                                              \
    { short8 av_[4] = {a0_, a1_, a2_, a3_};                                     \
      _Pragma("unroll")                                                         \
      for (int i_=0;i_<4;i_++){                                                 \
        _Pragma("unroll")                                                       \
        for (int j_=0;j_<4;j_++)                                                \
          acc[(QM)*4+i_][j_] = __builtin_amdgcn_mfma_f32_16x16x32_bf16(         \
              av_[i_], bv[j_], acc[(QM)*4+i_][j_], 0, 0, 0);                    \
      }                                                                         \
    }                                                                           \
    __builtin_amdgcn_s_setprio(0);                                              \
    if (TAILVM) asm volatile("s_waitcnt vmcnt(4)" ::: "memory");                \
    asm volatile("s_barrier" ::: "memory");                                     \
  } while(0)

  for (int it = 0; it < niter; ++it){
    const int u  = it*2;
    int u1 = u+1; if (u1 >= NT) u1 -= NT;
    int u2 = u+2; if (u2 >= NT) u2 -= NT;
    int u3 = u+3; if (u3 >= NT) u3 -= NT;
    const int k1 = u1*64, k2 = u2*64, k3 = u3*64;
    // compute tile u (buf0)
    PH(0, 0, 0, Ab, k1+32, 40960, 0);   // stage buf1.A.k1 (u+1)
    PH(0, 1, 0, Bb, k1+32, 57344, 0);   // stage buf1.B.k1 (u+1)
    PH(0, 0, 1, Ab, k2,    0,     0);   // stage buf0.A.k0 (u+2)
    PH(0, 1, 1, Bb, k2,    16384, 1);   // stage buf0.B.k0 (u+2); vmcnt(4)
    // compute tile u+1 (buf1)
    PH(1, 0, 0, Ab, k2+32, 8192,  0);   // stage buf0.A.k1 (u+2)
    PH(1, 1, 0, Bb, k2+32, 24576, 0);   // stage buf0.B.k1 (u+2)
    PH(1, 0, 1, Ab, k3,    32768, 0);   // stage buf1.A.k0 (u+3)
    PH(1, 1, 1, Bb, k3,    49152, 1);   // stage buf1.B.k0 (u+3); vmcnt(4)
  }
#undef PH

  // ---- epilogue: coalesce through LDS (XOR-swizzled 32-row staging) ----
  {
    char* sb = (char*)lds;
    constexpr int STRB = (OT==0) ? 1056 : 544;   // row stride bytes (pad chunks)
    const int tr = t >> 4, tcE = (t & 15) * 16;
    const int grow = m0 + (tr>>4)*128 + (tr&15); // + mi*16 added per mi
    #pragma unroll
    for (int mi = 0; mi < 8; ++mi){
      __syncthreads();
      #pragma unroll
      for (int nj = 0; nj < 4; ++nj){
        const int c = wc*64 + la + nj*16;
        float badd = (BIAS==1) ? bias[n0 + c] : 0.0f;
        #pragma unroll
        for (int j = 0; j < 4; ++j){
          const int lr = wr*16 + ((lane>>4)<<2) + j;
          float v = acc[mi][nj][j] * scale + badd;
          if (BIAS==2) v += bias[m0 + (lr>>4)*128 + mi*16 + (lr&15)];
          if constexpr (OT==0){
            const int byte = lr*STRB + ((((c>>2) ^ (lr&15)))<<4) + (c&3)*4;
            *reinterpret_cast<float*>(sb + byte) = v;
          } else if constexpr (OT==1){
            const int byte = lr*STRB + ((((c>>3) ^ (lr&15)))<<4) + (c&7)*2;
            *reinterpret_cast<__half*>(sb + byte) = __float2half(v);
          } else {
            const int byte = lr*STRB + ((((c>>3) ^ (lr&15)))<<4) + (c&7)*2;
            *reinterpret_cast<unsigned short*>(sb + byte) = f2bf(v);
          }
        }
      }
      __syncthreads();
      const long gbase = bz*sC + (long)(grow + mi*16)*N + n0 + tcE;
      if constexpr (OT==0){
        const int cb = tcE >> 2;
        #pragma unroll
        for (int i=0;i<4;i++){
          f32x4 vv = *reinterpret_cast<const f32x4*>(sb + tr*STRB + (((cb+i)^(tr&15))<<4));
          *reinterpret_cast<f32x4*>((float*)Cv + gbase + i*4) = vv;
        }
      } else {
        const int cb = tcE >> 3;
        #pragma unroll
        for (int i=0;i<2;i++){
          short8 vv = *reinterpret_cast<const short8*>(sb + tr*STRB + (((cb+i)^(tr&15))<<4));
          *reinterpret_cast<short8*>((unsigned short*)Cv + gbase + i*8) = vv;
        }
      }
    }
  }
}

// ---------------- row softmax, fp16 in -> bf16 out, in place ----------------
__global__ void softmax_rows(unsigned short* __restrict__ SP, int cols){
  const long row = blockIdx.x;
  unsigned short* rp = SP + row * cols;
  const int t = threadIdx.x, lane = t & 63, w = t >> 6;
  short8 raw = *reinterpret_cast<const short8*>(rp + t*8);
  float v[8];
  #pragma unroll
  for (int i=0;i<8;i++){
    unsigned short us = (unsigned short)raw[i];
    __half h; __builtin_memcpy(&h, &us, 2);
    v[i] = __half2float(h);
  }
  float m = v[0];
  #pragma unroll
  for (int i=1;i<8;i++) m = fmaxf(m, v[i]);
  #pragma unroll
  for (int o=32;o;o>>=1) m = fmaxf(m, __shfl_down(m, o));
  __shared__ float red[8];
  if (lane==0) red[w] = m;
  __syncthreads();
  if (t==0) red[4] = fmaxf(fmaxf(red[0],red[1]), fmaxf(red[2],red[3]));
  __syncthreads();
  const float rowmax = red[4];
  float s = 0.f;
  #pragma unroll
  for (int i=0;i<8;i++){ v[i] = __expf(v[i]-rowmax); s += v[i]; }
  #pragma unroll
  for (int o=32;o;o>>=1) s += __shfl_down(s, o);
  if (lane==0) red[w] = s;
  __syncthreads();
  if (t==0) red[5] = red[0]+red[1]+red[2]+red[3];
  __syncthreads();
  const float inv = 1.0f / red[5];
  short8 outp;
  #pragma unroll
  for (int i=0;i<8;i++) outp[i] = (short)f2bf(v[i]*inv);
  *reinterpret_cast<short8*>(rp + t*8) = outp;
}

extern "C" void kernel_launch(void* const* d_in, const int* in_sizes, int n_in,
                              void* d_out, int out_size, void* d_ws, size_t ws_size,
                              hipStream_t stream)
{
  const int B = 8, S = 2048, D = 1024;
  const int BS = B * S;                      // 16384
  const float* x1 = (const float*)d_in[0];
  const float* x2 = (const float*)d_in[1];
  const float* Wq = (const float*)d_in[2];
  const float* bq = (const float*)d_in[3];
  const float* Wk = (const float*)d_in[4];
  const float* bk = (const float*)d_in[5];
  const float* Wv = (const float*)d_in[6];
  const float* bv = (const float*)d_in[7];

  char* ws = (char*)d_ws;
  const size_t MB = 1024*1024;
  short*          x1b = (short*)(ws);             // 32MB (dead after q GEMM)
  short*          x2b = (short*)(ws + 32*MB);     // 32MB (dead after vT GEMM)
  unsigned short* Sc  = (unsigned short*)ws;      // 64MB scores/probs (reuses x1b/x2b)
  short*          q   = (short*)(ws + 64*MB);     // 32MB
  short*          k   = (short*)(ws + 96*MB);     // 32MB
  short*          vT  = (short*)(ws + 128*MB);    // 32MB [B][D][S]
  short*          WqT = (short*)(ws + 160*MB);
  short*          WkT = (short*)(ws + 162*MB);
  short*          WvT = (short*)(ws + 164*MB);    // total 166MB

  const size_t SH = 131072;  // 128KB dynamic LDS

  cast_f32_bf16<<<4096,256,0,stream>>>(x1, (unsigned short*)x1b, BS*D/4);
  cast_f32_bf16<<<4096,256,0,stream>>>(x2, (unsigned short*)x2b, BS*D/4);
  transpose_cast_w<<<dim3(32,32),256,0,stream>>>(Wq, (unsigned short*)WqT, D, D);
  transpose_cast_w<<<dim3(32,32),256,0,stream>>>(Wk, (unsigned short*)WkT, D, D);
  transpose_cast_w<<<dim3(32,32),256,0,stream>>>(Wv, (unsigned short*)WvT, D, D);

  // k2 = x2 @ Wk + bk (bf16): M=BS,N=D,K=D; grid 64x4 = 256
  gemm8<2,1><<<256, 512, SH, stream>>>(x2b, WkT, bk, k, D, D, 0,0,0, 1.0f, 64, 4);
  // vT[b] = WvT @ x2[b]^T + bv(per-row): M=D,N=S,K=D; grid 4x8x8 = 256
  gemm8<2,2><<<256, 512, SH, stream>>>(WvT, x2b, bv, vT, S, D, 0, (long)S*D, (long)D*S, 1.0f, 4, 8);
  // q1 = x1 @ Wq + bq: grid 256
  gemm8<2,1><<<256, 512, SH, stream>>>(x1b, WqT, bq, q, D, D, 0,0,0, 1.0f, 64, 4);
  // scores = q k^T / 32 (fp16): M=S,N=S,K=D; grid 8x8x8 = 512
  gemm8<1,0><<<512, 512, SH, stream>>>(q, k, nullptr, Sc, S, D,
                                       (long)S*D, (long)S*D, (long)S*S, 0.03125f, 8, 8);
  // softmax rows, in place -> bf16 probs
  softmax_rows<<<BS,256,0,stream>>>(Sc, S);
  // O = P @ V: A=P[S,S] bf16, Bt=vT[D,S], C=f32 out: M=S,N=D,K=S; grid 8x4x8 = 256
  gemm8<0,0><<<256, 512, SH, stream>>>((short*)Sc, vT, nullptr, d_out, D, S,
                                       (long)S*S, (long)D*S, (long)S*D, 1.0f, 8, 4);
}

// Round 4
// 342.746 us; speedup vs baseline: 1.0110x; 1.0110x over previous
//
#include <hip/hip_runtime.h>
#include <hip/hip_bf16.h>
#include <hip/hip_fp16.h>

typedef __attribute__((ext_vector_type(8))) short short8;
typedef __attribute__((ext_vector_type(4))) float f32x4;

#define DEVI __device__ __forceinline__

DEVI unsigned short f2bf(float f){
  __hip_bfloat16 h = __float2bfloat16(f);
  unsigned short u; __builtin_memcpy(&u, &h, 2); return u;
}

// ---------------- cast fp32 -> bf16 ----------------
__global__ void cast_f32_bf16(const float* __restrict__ in, unsigned short* __restrict__ out, int n4){
  int stride = gridDim.x * blockDim.x;
  for (int i = blockIdx.x*blockDim.x + threadIdx.x; i < n4; i += stride){
    float4 f = reinterpret_cast<const float4*>(in)[i];
    ushort4 o;
    o.x = f2bf(f.x); o.y = f2bf(f.y); o.z = f2bf(f.z); o.w = f2bf(f.w);
    reinterpret_cast<ushort4*>(out)[i] = o;
  }
}

// ---------------- transpose + cast: WT[n][k] = W[k][n] ----------------
__global__ void transpose_cast_w(const float* __restrict__ W, unsigned short* __restrict__ WT, int K, int N){
  __shared__ float tile[32][33];
  int bn = blockIdx.x*32, bk = blockIdx.y*32;
  int tx = threadIdx.x & 31, ty = threadIdx.x >> 5;
  for (int r=0;r<32;r+=8)
    tile[ty+r][tx] = W[(long)(bk+ty+r)*N + bn+tx];
  __syncthreads();
  for (int r=0;r<32;r+=8)
    WT[(long)(bn+ty+r)*K + bk+tx] = (short)f2bf(tile[tx][ty+r]);
}

// ---------------- async global->LDS, 16B/lane ----------------
DEVI void stage16(const short* gsrc, short* lbase){
  __builtin_amdgcn_global_load_lds(
      (const __attribute__((address_space(1))) unsigned int*)gsrc,
      (__attribute__((address_space(3))) unsigned int*)lbase, 16, 0, 0);
}

// Stage one 16KB K-half block (256 rows x 32 kelems) with precomputed offsets.
DEVI void stage2(const short* base, long o0, long o1, short* blk, int w){
  stage16(base + o0, blk + w*512);
  stage16(base + o1, blk + (8+w)*512);
}

// ---------------- 256x256 8-phase GEMM: C = scale*(A @ Bt^T) + bias ----------
// OT: 0=f32, 1=f16, 2=bf16.  BIAS: 0 none, 1 per-col, 2 per-row.
// BK=64 (2 K-halves), 512 thr = 8 waves (2M x 4N), dbuf LDS 128KB.
// LDS block idx = buf*4 + op*2 + khalf (op 0=A,1=B), 8192 shorts (16KB) each.
// Phase-pair: 12 ds_reads batched at QM0, counted lgkmcnt(4) so the QM1
// A-reads drain under the QM0 MFMA cluster; ONE s_barrier per phase.
template<int OT, int BIAS>
__global__ __launch_bounds__(512, 2)
void gemm8(const short* __restrict__ A, const short* __restrict__ Bt,
           const float* __restrict__ bias, void* __restrict__ Cv,
           int N, int K, long sA, long sB, long sC, float scale, int nx, int ny)
{
  extern __shared__ short lds[];
  // bijective XCD swizzle (all launches have nwg % 8 == 0)
  const int nwg = gridDim.x;
  const int cpx = nwg >> 3;
  const int wg  = (blockIdx.x & 7)*cpx + (blockIdx.x >> 3);
  const int bx  = wg % nx;
  const int tmp = wg / nx;
  const int by  = tmp % ny;
  const long bz = tmp / ny;
  const int m0 = bx * 256, n0 = by * 256;
  const short* Ab = A  + bz*sA + (long)m0 * K;
  const short* Bb = Bt + bz*sB + (long)n0 * K;

  const int t = threadIdx.x, lane = t & 63, w = t >> 6;
  const int wr = w >> 2, wc = w & 3;            // 2M x 4N wave grid

  // staging invariants: chunk rows + pre-swizzled k (st_16x32 involution)
  const int rr = lane >> 2;
  const int kk = ((lane & 3) * 8) ^ ((lane & 32) ? 16 : 0);
  const long off0 = (long)(( w     )*16 + rr) * K + kk;
  const long off1 = (long)(( 8 + w )*16 + rr) * K + kk;

  // ds_read invariants: swizzled per-lane byte offset within each 1KB subtile
  const int la = lane & 15;
  const int lsw = (la*64 + ((lane>>4)<<4)) ^ ((la>=8)?32:0);
  const short* AP = lds + (lsw>>1) + wr*4096;           // + rowblk*512 per frag
  const short* BP = lds + (lsw>>1) + 16384 + wc*2048;   // B blocks start at blk2

  f32x4 acc[8][4] = {};

  const int NT = K >> 6;          // K-tiles of 64
  const int niter = NT >> 1;      // 2 K-tiles per iteration

  // ---- prologue: tile0 -> buf0 (A.k0,B.k0,A.k1,B.k1), tile1 k0 -> buf1 ----
  stage2(Ab,      off0, off1, lds + 0,     w);
  stage2(Bb,      off0, off1, lds + 16384, w);
  stage2(Ab + 32, off0, off1, lds + 8192,  w);
  stage2(Bb + 32, off0, off1, lds + 24576, w);
  stage2(Ab + 64, off0, off1, lds + 32768, w);
  stage2(Bb + 64, off0, off1, lds + 49152, w);
  asm volatile("s_waitcnt vmcnt(4)" ::: "memory");   // buf0 fully landed
  asm volatile("s_barrier" ::: "memory");

#define MFMA4(MI, AV)                                                           \
    acc[MI][0] = __builtin_amdgcn_mfma_f32_16x16x32_bf16(AV, b0_, acc[MI][0], 0,0,0); \
    acc[MI][1] = __builtin_amdgcn_mfma_f32_16x16x32_bf16(AV, b1_, acc[MI][1], 0,0,0); \
    acc[MI][2] = __builtin_amdgcn_mfma_f32_16x16x32_bf16(AV, b2_, acc[MI][2], 0,0,0); \
    acc[MI][3] = __builtin_amdgcn_mfma_f32_16x16x32_bf16(AV, b3_, acc[MI][3], 0,0,0);

#define PHPAIR(CBUF, QK, SB0, SO0, SL0, SB1, SO1, SL1, TAILVM) do {             \
    const short* bp_ = BP + (CBUF)*32768 + (QK)*8192;                           \
    short8 b0_ = *reinterpret_cast<const short8*>(bp_ + 0*512);                 \
    short8 b1_ = *reinterpret_cast<const short8*>(bp_ + 1*512);                 \
    short8 b2_ = *reinterpret_cast<const short8*>(bp_ + 2*512);                 \
    short8 b3_ = *reinterpret_cast<const short8*>(bp_ + 3*512);                 \
    const short* ap_ = AP + (CBUF)*32768 + (QK)*8192;                           \
    short8 a0_ = *reinterpret_cast<const short8*>(ap_ + 0*512);                 \
    short8 a1_ = *reinterpret_cast<const short8*>(ap_ + 1*512);                 \
    short8 a2_ = *reinterpret_cast<const short8*>(ap_ + 2*512);                 \
    short8 a3_ = *reinterpret_cast<const short8*>(ap_ + 3*512);                 \
    short8 a4_ = *reinterpret_cast<const short8*>(ap_ + 2048 + 0*512);          \
    short8 a5_ = *reinterpret_cast<const short8*>(ap_ + 2048 + 1*512);          \
    short8 a6_ = *reinterpret_cast<const short8*>(ap_ + 2048 + 2*512);          \
    short8 a7_ = *reinterpret_cast<const short8*>(ap_ + 2048 + 3*512);          \
    stage2((SB0) + (SO0), off0, off1, lds + (SL0), w);                          \
    asm volatile("s_waitcnt lgkmcnt(4)" ::: "memory");                          \
    __builtin_amdgcn_sched_barrier(0);                                          \
    __builtin_amdgcn_s_setprio(1);                                              \
    MFMA4(0, a0_) MFMA4(1, a1_) MFMA4(2, a2_) MFMA4(3, a3_)                     \
    __builtin_amdgcn_s_setprio(0);                                              \
    __builtin_amdgcn_sched_barrier(0);                                          \
    asm volatile("s_barrier" ::: "memory");                                     \
    stage2((SB1) + (SO1), off0, off1, lds + (SL1), w);                          \
    asm volatile("s_waitcnt lgkmcnt(0)" ::: "memory");                          \
    __builtin_amdgcn_sched_barrier(0);                                          \
    __builtin_amdgcn_s_setprio(1);                                              \
    MFMA4(4, a4_) MFMA4(5, a5_) MFMA4(6, a6_) MFMA4(7, a7_)                     \
    __builtin_amdgcn_s_setprio(0);                                              \
    __builtin_amdgcn_sched_barrier(0);                                          \
    if (TAILVM) asm volatile("s_waitcnt vmcnt(4)" ::: "memory");                \
    asm volatile("s_barrier" ::: "memory");                                     \
  } while(0)

  for (int it = 0; it < niter; ++it){
    const int u  = it*2;
    int u1 = u+1; if (u1 >= NT) u1 -= NT;
    int u2 = u+2; if (u2 >= NT) u2 -= NT;
    int u3 = u+3; if (u3 >= NT) u3 -= NT;
    const int k1 = u1*64, k2 = u2*64, k3 = u3*64;
    // compute tile u (buf0): phases 1-4
    PHPAIR(0, 0, Ab, k1+32, 40960, Bb, k1+32, 57344, 0);  // stage buf1.A.k1, buf1.B.k1
    PHPAIR(0, 1, Ab, k2,    0,     Bb, k2,    16384, 1);  // stage buf0'.A.k0, buf0'.B.k0; vm(4)
    // compute tile u+1 (buf1): phases 5-8
    PHPAIR(1, 0, Ab, k2+32, 8192,  Bb, k2+32, 24576, 0);  // stage buf0'.A.k1, buf0'.B.k1
    PHPAIR(1, 1, Ab, k3,    32768, Bb, k3,    49152, 1);  // stage buf1'.A.k0, buf1'.B.k0; vm(4)
  }
#undef PHPAIR
#undef MFMA4

  // drain outstanding staging writes before reusing LDS for the epilogue
  asm volatile("s_waitcnt vmcnt(0) lgkmcnt(0)" ::: "memory");
  __syncthreads();

  // ---- epilogue: coalesce through LDS (XOR-swizzled 32-row staging) ----
  {
    char* sb = (char*)lds;
    constexpr int STRB = (OT==0) ? 1056 : 544;   // row stride bytes (pad chunks)
    const int tr = t >> 4, tcE = (t & 15) * 16;
    const int grow = m0 + (tr>>4)*128 + (tr&15); // + mi*16 added per mi
    #pragma unroll
    for (int mi = 0; mi < 8; ++mi){
      __syncthreads();
      #pragma unroll
      for (int nj = 0; nj < 4; ++nj){
        const int c = wc*64 + la + nj*16;
        float badd = (BIAS==1) ? bias[n0 + c] : 0.0f;
        #pragma unroll
        for (int j = 0; j < 4; ++j){
          const int lr = wr*16 + ((lane>>4)<<2) + j;
          float v = acc[mi][nj][j] * scale + badd;
          if (BIAS==2) v += bias[m0 + (lr>>4)*128 + mi*16 + (lr&15)];
          if constexpr (OT==0){
            const int byte = lr*STRB + ((((c>>2) ^ (lr&15)))<<4) + (c&3)*4;
            *reinterpret_cast<float*>(sb + byte) = v;
          } else if constexpr (OT==1){
            const int byte = lr*STRB + ((((c>>3) ^ (lr&15)))<<4) + (c&7)*2;
            *reinterpret_cast<__half*>(sb + byte) = __float2half(v);
          } else {
            const int byte = lr*STRB + ((((c>>3) ^ (lr&15)))<<4) + (c&7)*2;
            *reinterpret_cast<unsigned short*>(sb + byte) = f2bf(v);
          }
        }
      }
      __syncthreads();
      const long gbase = bz*sC + (long)(grow + mi*16)*N + n0 + tcE;
      if constexpr (OT==0){
        const int cb = tcE >> 2;
        #pragma unroll
        for (int i=0;i<4;i++){
          f32x4 vv = *reinterpret_cast<const f32x4*>(sb + tr*STRB + (((cb+i)^(tr&15))<<4));
          *reinterpret_cast<f32x4*>((float*)Cv + gbase + i*4) = vv;
        }
      } else {
        const int cb = tcE >> 3;
        #pragma unroll
        for (int i=0;i<2;i++){
          short8 vv = *reinterpret_cast<const short8*>(sb + tr*STRB + (((cb+i)^(tr&15))<<4));
          *reinterpret_cast<short8*>((unsigned short*)Cv + gbase + i*8) = vv;
        }
      }
    }
  }
}

// ---------------- row softmax, fp16 in -> bf16 out, in place ----------------
__global__ void softmax_rows(unsigned short* __restrict__ SP, int cols){
  const long row = blockIdx.x;
  unsigned short* rp = SP + row * cols;
  const int t = threadIdx.x, lane = t & 63, w = t >> 6;
  short8 raw = *reinterpret_cast<const short8*>(rp + t*8);
  float v[8];
  #pragma unroll
  for (int i=0;i<8;i++){
    unsigned short us = (unsigned short)raw[i];
    __half h; __builtin_memcpy(&h, &us, 2);
    v[i] = __half2float(h);
  }
  float m = v[0];
  #pragma unroll
  for (int i=1;i<8;i++) m = fmaxf(m, v[i]);
  #pragma unroll
  for (int o=32;o;o>>=1) m = fmaxf(m, __shfl_down(m, o));
  __shared__ float red[8];
  if (lane==0) red[w] = m;
  __syncthreads();
  if (t==0) red[4] = fmaxf(fmaxf(red[0],red[1]), fmaxf(red[2],red[3]));
  __syncthreads();
  const float rowmax = red[4];
  float s = 0.f;
  #pragma unroll
  for (int i=0;i<8;i++){ v[i] = __expf(v[i]-rowmax); s += v[i]; }
  #pragma unroll
  for (int o=32;o;o>>=1) s += __shfl_down(s, o);
  if (lane==0) red[w] = s;
  __syncthreads();
  if (t==0) red[5] = red[0]+red[1]+red[2]+red[3];
  __syncthreads();
  const float inv = 1.0f / red[5];
  short8 outp;
  #pragma unroll
  for (int i=0;i<8;i++) outp[i] = (short)f2bf(v[i]*inv);
  *reinterpret_cast<short8*>(rp + t*8) = outp;
}

extern "C" void kernel_launch(void* const* d_in, const int* in_sizes, int n_in,
                              void* d_out, int out_size, void* d_ws, size_t ws_size,
                              hipStream_t stream)
{
  const int B = 8, S = 2048, D = 1024;
  const int BS = B * S;                      // 16384
  const float* x1 = (const float*)d_in[0];
  const float* x2 = (const float*)d_in[1];
  const float* Wq = (const float*)d_in[2];
  const float* bq = (const float*)d_in[3];
  const float* Wk = (const float*)d_in[4];
  const float* bk = (const float*)d_in[5];
  const float* Wv = (const float*)d_in[6];
  const float* bv = (const float*)d_in[7];

  char* ws = (char*)d_ws;
  const size_t MB = 1024*1024;
  short*          x1b = (short*)(ws);             // 32MB (dead after q GEMM)
  short*          x2b = (short*)(ws + 32*MB);     // 32MB (dead after vT GEMM)
  unsigned short* Sc  = (unsigned short*)ws;      // 64MB scores/probs (reuses x1b/x2b)
  short*          q   = (short*)(ws + 64*MB);     // 32MB
  short*          k   = (short*)(ws + 96*MB);     // 32MB
  short*          vT  = (short*)(ws + 128*MB);    // 32MB [B][D][S]
  short*          WqT = (short*)(ws + 160*MB);
  short*          WkT = (short*)(ws + 162*MB);
  short*          WvT = (short*)(ws + 164*MB);    // total 166MB

  const size_t SH = 131072;  // 128KB dynamic LDS

  cast_f32_bf16<<<4096,256,0,stream>>>(x1, (unsigned short*)x1b, BS*D/4);
  cast_f32_bf16<<<4096,256,0,stream>>>(x2, (unsigned short*)x2b, BS*D/4);
  transpose_cast_w<<<dim3(32,32),256,0,stream>>>(Wq, (unsigned short*)WqT, D, D);
  transpose_cast_w<<<dim3(32,32),256,0,stream>>>(Wk, (unsigned short*)WkT, D, D);
  transpose_cast_w<<<dim3(32,32),256,0,stream>>>(Wv, (unsigned short*)WvT, D, D);

  // k2 = x2 @ Wk + bk (bf16): M=BS,N=D,K=D; grid 64x4 = 256
  gemm8<2,1><<<256, 512, SH, stream>>>(x2b, WkT, bk, k, D, D, 0,0,0, 1.0f, 64, 4);
  // vT[b] = WvT @ x2[b]^T + bv(per-row): M=D,N=S,K=D; grid 4x8x8 = 256
  gemm8<2,2><<<256, 512, SH, stream>>>(WvT, x2b, bv, vT, S, D, 0, (long)S*D, (long)D*S, 1.0f, 4, 8);
  // q1 = x1 @ Wq + bq: grid 256
  gemm8<2,1><<<256, 512, SH, stream>>>(x1b, WqT, bq, q, D, D, 0,0,0, 1.0f, 64, 4);
  // scores = q k^T / 32 (fp16): M=S,N=S,K=D; grid 8x8x8 = 512
  gemm8<1,0><<<512, 512, SH, stream>>>(q, k, nullptr, Sc, S, D,
                                       (long)S*D, (long)S*D, (long)S*S, 0.03125f, 8, 8);
  // softmax rows, in place -> bf16 probs
  softmax_rows<<<BS,256,0,stream>>>(Sc, S);
  // O = P @ V: A=P[S,S] bf16, Bt=vT[D,S], C=f32 out: M=S,N=D,K=S; grid 8x4x8 = 256
  gemm8<0,0><<<256, 512, SH, stream>>>((short*)Sc, vT, nullptr, d_out, D, S,
                                       (long)S*S, (long)D*S, (long)S*D, 1.0f, 8, 4);
}

// Round 5
// 340.935 us; speedup vs baseline: 1.0164x; 1.0053x over previous
//
#include <hip/hip_runtime.h>
#include <hip/hip_bf16.h>
#include <hip/hip_fp16.h>

typedef __attribute__((ext_vector_type(8))) short short8;
typedef __attribute__((ext_vector_type(4))) float f32x4;

#define DEVI __device__ __forceinline__

DEVI unsigned short f2bf(float f){
  __hip_bfloat16 h = __float2bfloat16(f);
  unsigned short u; __builtin_memcpy(&u, &h, 2); return u;
}

// ---------------- cast fp32 -> bf16 ----------------
__global__ void cast_f32_bf16(const float* __restrict__ in, unsigned short* __restrict__ out, int n4){
  int stride = gridDim.x * blockDim.x;
  for (int i = blockIdx.x*blockDim.x + threadIdx.x; i < n4; i += stride){
    float4 f = reinterpret_cast<const float4*>(in)[i];
    ushort4 o;
    o.x = f2bf(f.x); o.y = f2bf(f.y); o.z = f2bf(f.z); o.w = f2bf(f.w);
    reinterpret_cast<ushort4*>(out)[i] = o;
  }
}

// ---------------- transpose + cast: WT[n][k] = W[k][n] ----------------
__global__ void transpose_cast_w(const float* __restrict__ W, unsigned short* __restrict__ WT, int K, int N){
  __shared__ float tile[32][33];
  int bn = blockIdx.x*32, bk = blockIdx.y*32;
  int tx = threadIdx.x & 31, ty = threadIdx.x >> 5;
  for (int r=0;r<32;r+=8)
    tile[ty+r][tx] = W[(long)(bk+ty+r)*N + bn+tx];
  __syncthreads();
  for (int r=0;r<32;r+=8)
    WT[(long)(bn+ty+r)*K + bk+tx] = (short)f2bf(tile[tx][ty+r]);
}

// ---------------- async global->LDS, 16B/lane ----------------
DEVI void stage16(const short* gsrc, short* lbase){
  __builtin_amdgcn_global_load_lds(
      (const __attribute__((address_space(1))) unsigned int*)gsrc,
      (__attribute__((address_space(3))) unsigned int*)lbase, 16, 0, 0);
}

// Stage one 16KB K-half block (256 rows x 32 kelems) with precomputed offsets.
DEVI void stage2(const short* base, long o0, long o1, short* blk, int w){
  stage16(base + o0, blk + w*512);
  stage16(base + o1, blk + (8+w)*512);
}

// ---------------- 256x256 8-phase GEMM, frag-loads pipelined 1 phase ahead --
// OT: 0=f32, 1=f16, 2=bf16.  BIAS: 0 none, 1 per-col, 2 per-row.
// BK=64 (2 K-halves), 512 thr = 8 waves (2M x 4N), dbuf LDS 128KB.
// LDS block idx = buf*4 + op*2 + khalf (op 0=A,1=B), 8192 shorts (16KB) each.
// Phase p issues ds_reads for phase p+1's fragments; waits lgkmcnt(J_issued)
// so the PREVIOUS phase's reads (used by this phase's MFMA) are drained while
// this phase's reads stream under the MFMA cluster. vmcnt(4) every 2nd phase.
template<int OT, int BIAS>
__global__ __launch_bounds__(512, 2)
void gemm8(const short* __restrict__ A, const short* __restrict__ Bt,
           const float* __restrict__ bias, void* __restrict__ Cv,
           int N, int K, long sA, long sB, long sC, float scale, int nx, int ny)
{
  extern __shared__ short lds[];
  // bijective XCD swizzle (all launches have nwg % 8 == 0)
  const int nwg = gridDim.x;
  const int cpx = nwg >> 3;
  const int wg  = (blockIdx.x & 7)*cpx + (blockIdx.x >> 3);
  const int bx  = wg % nx;
  const int tmp = wg / nx;
  const int by  = tmp % ny;
  const long bz = tmp / ny;
  const int m0 = bx * 256, n0 = by * 256;
  const short* Ab = A  + bz*sA + (long)m0 * K;
  const short* Bb = Bt + bz*sB + (long)n0 * K;

  const int t = threadIdx.x, lane = t & 63, w = t >> 6;
  const int wr = w >> 2, wc = w & 3;            // 2M x 4N wave grid

  // staging invariants: chunk rows + pre-swizzled k (st_16x32 involution)
  const int rr = lane >> 2;
  const int kk = ((lane & 3) * 8) ^ ((lane & 32) ? 16 : 0);
  const long off0 = (long)(( w     )*16 + rr) * K + kk;
  const long off1 = (long)(( 8 + w )*16 + rr) * K + kk;

  // ds_read invariants: swizzled per-lane byte offset within each 1KB subtile
  const int la = lane & 15;
  const int lsw = (la*64 + ((lane>>4)<<4)) ^ ((la>=8)?32:0);
  const short* AP = lds + (lsw>>1) + wr*4096;           // + rowblk*512 per frag
  const short* BP = lds + (lsw>>1) + 16384 + wc*2048;   // B blocks start at blk2

  f32x4 acc[8][4] = {};

  const int NT = K >> 6;          // K-tiles of 64
  const int niter = NT >> 1;      // 2 K-tiles per iteration

  // ---- prologue: tile0 -> buf0 (A.k0,B.k0,A.k1,B.k1), tile1 k0 -> buf1 ----
  stage2(Ab,      off0, off1, lds + 0,     w);
  stage2(Bb,      off0, off1, lds + 16384, w);
  stage2(Ab + 32, off0, off1, lds + 8192,  w);
  stage2(Bb + 32, off0, off1, lds + 24576, w);
  stage2(Ab + 64, off0, off1, lds + 32768, w);
  stage2(Bb + 64, off0, off1, lds + 49152, w);
  asm volatile("s_waitcnt vmcnt(4)" ::: "memory");   // buf0 (k0+k1) landed
  asm volatile("s_barrier" ::: "memory");

  // fragment register sets
  short8 Bx0,Bx1,Bx2,Bx3, A0x0,A0x1,A0x2,A0x3;
  short8 By0,By1,By2,By3, A0y0,A0y1,A0y2,A0y3;
  short8 A10,A11,A12,A13;

#define RD4(d0,d1,d2,d3, P) \
    d0 = *reinterpret_cast<const short8*>((P) + 0*512); \
    d1 = *reinterpret_cast<const short8*>((P) + 1*512); \
    d2 = *reinterpret_cast<const short8*>((P) + 2*512); \
    d3 = *reinterpret_cast<const short8*>((P) + 3*512);

  // prologue frag reads: h1 = (buf0, k0)
  RD4(Bx0,Bx1,Bx2,Bx3, BP)
  RD4(A0x0,A0x1,A0x2,A0x3, AP)

#define MM4(MI, AV, C0,C1,C2,C3) \
    acc[MI][0] = __builtin_amdgcn_mfma_f32_16x16x32_bf16(AV, C0, acc[MI][0], 0,0,0); \
    acc[MI][1] = __builtin_amdgcn_mfma_f32_16x16x32_bf16(AV, C1, acc[MI][1], 0,0,0); \
    acc[MI][2] = __builtin_amdgcn_mfma_f32_16x16x32_bf16(AV, C2, acc[MI][2], 0,0,0); \
    acc[MI][3] = __builtin_amdgcn_mfma_f32_16x16x32_bf16(AV, C3, acc[MI][3], 0,0,0);

// PH_A: MFMA QM0 (acc rows 0-3) with (B*, A0*); read A1 frags of CURRENT half.
#define PH_A(B0,B1,B2,B3, Q0,Q1,Q2,Q3, CBUF, QK, SBASE, SOFF, SL) do {          \
    const short* a1p_ = AP + (CBUF)*32768 + (QK)*8192 + 2048;                   \
    RD4(A10,A11,A12,A13, a1p_)                                                  \
    stage2((SBASE) + (SOFF), off0, off1, lds + (SL), w);                        \
    asm volatile("s_waitcnt lgkmcnt(4)" ::: "memory");                          \
    __builtin_amdgcn_s_setprio(1);                                              \
    MM4(0, Q0, B0,B1,B2,B3) MM4(1, Q1, B0,B1,B2,B3)                             \
    MM4(2, Q2, B0,B1,B2,B3) MM4(3, Q3, B0,B1,B2,B3)                             \
    __builtin_amdgcn_s_setprio(0);                                              \
    asm volatile("s_barrier" ::: "memory");                                     \
  } while(0)

// PH_B: MFMA QM1 (acc rows 4-7) with (B*, A1); read NEXT half's B and A0 frags.
#define PH_B(B0,B1,B2,B3, N0,N1,N2,N3, P0,P1,P2,P3, NCBUF, NQK, SBASE, SOFF, SL) do { \
    const short* bp_ = BP + (NCBUF)*32768 + (NQK)*8192;                         \
    const short* ap_ = AP + (NCBUF)*32768 + (NQK)*8192;                         \
    RD4(N0,N1,N2,N3, bp_)                                                       \
    RD4(P0,P1,P2,P3, ap_)                                                       \
    stage2((SBASE) + (SOFF), off0, off1, lds + (SL), w);                        \
    asm volatile("s_waitcnt lgkmcnt(8)" ::: "memory");                          \
    __builtin_amdgcn_s_setprio(1);                                              \
    MM4(4, A10, B0,B1,B2,B3) MM4(5, A11, B0,B1,B2,B3)                           \
    MM4(6, A12, B0,B1,B2,B3) MM4(7, A13, B0,B1,B2,B3)                           \
    __builtin_amdgcn_s_setprio(0);                                              \
    asm volatile("s_waitcnt vmcnt(4)" ::: "memory");                            \
    asm volatile("s_barrier" ::: "memory");                                     \
  } while(0)

  for (int it = 0; it < niter; ++it){
    const int u  = it*2;
    int u1 = u+1; if (u1 >= NT) u1 -= NT;
    int u2 = u+2; if (u2 >= NT) u2 -= NT;
    int u3 = u+3; if (u3 >= NT) u3 -= NT;
    const int k1 = u1*64, k2 = u2*64, k3 = u3*64;
    // h1=(buf0,k0) h2=(buf0,k1) h3=(buf1,k0) h4=(buf1,k1)
    PH_A(Bx0,Bx1,Bx2,Bx3, A0x0,A0x1,A0x2,A0x3, 0,0, Ab, k1+32, 40960);   // st buf1.A.k1
    PH_B(Bx0,Bx1,Bx2,Bx3, By0,By1,By2,By3, A0y0,A0y1,A0y2,A0y3, 0,1,
         Bb, k1+32, 57344);                                              // st buf1.B.k1
    PH_A(By0,By1,By2,By3, A0y0,A0y1,A0y2,A0y3, 0,1, Ab, k2, 0);          // st buf0'.A.k0
    PH_B(By0,By1,By2,By3, Bx0,Bx1,Bx2,Bx3, A0x0,A0x1,A0x2,A0x3, 1,0,
         Bb, k2, 16384);                                                 // st buf0'.B.k0
    PH_A(Bx0,Bx1,Bx2,Bx3, A0x0,A0x1,A0x2,A0x3, 1,0, Ab, k2+32, 8192);    // st buf0'.A.k1
    PH_B(Bx0,Bx1,Bx2,Bx3, By0,By1,By2,By3, A0y0,A0y1,A0y2,A0y3, 1,1,
         Bb, k2+32, 24576);                                              // st buf0'.B.k1
    PH_A(By0,By1,By2,By3, A0y0,A0y1,A0y2,A0y3, 1,1, Ab, k3, 32768);      // st buf1'.A.k0
    PH_B(By0,By1,By2,By3, Bx0,Bx1,Bx2,Bx3, A0x0,A0x1,A0x2,A0x3, 0,0,
         Bb, k3, 49152);                                                 // st buf1'.B.k0
  }
#undef PH_A
#undef PH_B
#undef MM4
#undef RD4

  // drain outstanding staging before reusing LDS for the epilogue
  asm volatile("s_waitcnt vmcnt(0) lgkmcnt(0)" ::: "memory");
  __syncthreads();

  // ---- epilogue: coalesce through LDS (XOR-swizzled 32-row staging) ----
  {
    char* sb = (char*)lds;
    constexpr int STRB = (OT==0) ? 1056 : 544;   // row stride bytes (pad chunks)
    const int tr = t >> 4, tcE = (t & 15) * 16;
    const int grow = m0 + (tr>>4)*128 + (tr&15); // + mi*16 added per mi
    #pragma unroll
    for (int mi = 0; mi < 8; ++mi){
      __syncthreads();
      #pragma unroll
      for (int nj = 0; nj < 4; ++nj){
        const int c = wc*64 + la + nj*16;
        float badd = (BIAS==1) ? bias[n0 + c] : 0.0f;
        #pragma unroll
        for (int j = 0; j < 4; ++j){
          const int lr = wr*16 + ((lane>>4)<<2) + j;
          float v = acc[mi][nj][j] * scale + badd;
          if (BIAS==2) v += bias[m0 + (lr>>4)*128 + mi*16 + (lr&15)];
          if constexpr (OT==0){
            const int byte = lr*STRB + ((((c>>2) ^ (lr&15)))<<4) + (c&3)*4;
            *reinterpret_cast<float*>(sb + byte) = v;
          } else if constexpr (OT==1){
            const int byte = lr*STRB + ((((c>>3) ^ (lr&15)))<<4) + (c&7)*2;
            *reinterpret_cast<__half*>(sb + byte) = __float2half(v);
          } else {
            const int byte = lr*STRB + ((((c>>3) ^ (lr&15)))<<4) + (c&7)*2;
            *reinterpret_cast<unsigned short*>(sb + byte) = f2bf(v);
          }
        }
      }
      __syncthreads();
      const long gbase = bz*sC + (long)(grow + mi*16)*N + n0 + tcE;
      if constexpr (OT==0){
        const int cb = tcE >> 2;
        #pragma unroll
        for (int i=0;i<4;i++){
          f32x4 vv = *reinterpret_cast<const f32x4*>(sb + tr*STRB + (((cb+i)^(tr&15))<<4));
          *reinterpret_cast<f32x4*>((float*)Cv + gbase + i*4) = vv;
        }
      } else {
        const int cb = tcE >> 3;
        #pragma unroll
        for (int i=0;i<2;i++){
          short8 vv = *reinterpret_cast<const short8*>(sb + tr*STRB + (((cb+i)^(tr&15))<<4));
          *reinterpret_cast<short8*>((unsigned short*)Cv + gbase + i*8) = vv;
        }
      }
    }
  }
}

// ---------------- row softmax, fp16 in -> bf16 out, in place ----------------
__global__ void softmax_rows(unsigned short* __restrict__ SP, int cols){
  const long row = blockIdx.x;
  unsigned short* rp = SP + row * cols;
  const int t = threadIdx.x, lane = t & 63, w = t >> 6;
  short8 raw = *reinterpret_cast<const short8*>(rp + t*8);
  float v[8];
  #pragma unroll
  for (int i=0;i<8;i++){
    unsigned short us = (unsigned short)raw[i];
    __half h; __builtin_memcpy(&h, &us, 2);
    v[i] = __half2float(h);
  }
  float m = v[0];
  #pragma unroll
  for (int i=1;i<8;i++) m = fmaxf(m, v[i]);
  #pragma unroll
  for (int o=32;o;o>>=1) m = fmaxf(m, __shfl_down(m, o));
  __shared__ float red[8];
  if (lane==0) red[w] = m;
  __syncthreads();
  if (t==0) red[4] = fmaxf(fmaxf(red[0],red[1]), fmaxf(red[2],red[3]));
  __syncthreads();
  const float rowmax = red[4];
  float s = 0.f;
  #pragma unroll
  for (int i=0;i<8;i++){ v[i] = __expf(v[i]-rowmax); s += v[i]; }
  #pragma unroll
  for (int o=32;o;o>>=1) s += __shfl_down(s, o);
  if (lane==0) red[w] = s;
  __syncthreads();
  if (t==0) red[5] = red[0]+red[1]+red[2]+red[3];
  __syncthreads();
  const float inv = 1.0f / red[5];
  short8 outp;
  #pragma unroll
  for (int i=0;i<8;i++) outp[i] = (short)f2bf(v[i]*inv);
  *reinterpret_cast<short8*>(rp + t*8) = outp;
}

extern "C" void kernel_launch(void* const* d_in, const int* in_sizes, int n_in,
                              void* d_out, int out_size, void* d_ws, size_t ws_size,
                              hipStream_t stream)
{
  const int B = 8, S = 2048, D = 1024;
  const int BS = B * S;                      // 16384
  const float* x1 = (const float*)d_in[0];
  const float* x2 = (const float*)d_in[1];
  const float* Wq = (const float*)d_in[2];
  const float* bq = (const float*)d_in[3];
  const float* Wk = (const float*)d_in[4];
  const float* bk = (const float*)d_in[5];
  const float* Wv = (const float*)d_in[6];
  const float* bv = (const float*)d_in[7];

  char* ws = (char*)d_ws;
  const size_t MB = 1024*1024;
  short*          x1b = (short*)(ws);             // 32MB (dead after q GEMM)
  short*          x2b = (short*)(ws + 32*MB);     // 32MB (dead after vT GEMM)
  unsigned short* Sc  = (unsigned short*)ws;      // 64MB scores/probs (reuses x1b/x2b)
  short*          q   = (short*)(ws + 64*MB);     // 32MB
  short*          k   = (short*)(ws + 96*MB);     // 32MB
  short*          vT  = (short*)(ws + 128*MB);    // 32MB [B][D][S]
  short*          WqT = (short*)(ws + 160*MB);
  short*          WkT = (short*)(ws + 162*MB);
  short*          WvT = (short*)(ws + 164*MB);    // total 166MB

  const size_t SH = 131072;  // 128KB dynamic LDS

  cast_f32_bf16<<<4096,256,0,stream>>>(x1, (unsigned short*)x1b, BS*D/4);
  cast_f32_bf16<<<4096,256,0,stream>>>(x2, (unsigned short*)x2b, BS*D/4);
  transpose_cast_w<<<dim3(32,32),256,0,stream>>>(Wq, (unsigned short*)WqT, D, D);
  transpose_cast_w<<<dim3(32,32),256,0,stream>>>(Wk, (unsigned short*)WkT, D, D);
  transpose_cast_w<<<dim3(32,32),256,0,stream>>>(Wv, (unsigned short*)WvT, D, D);

  // k2 = x2 @ Wk + bk (bf16): M=BS,N=D,K=D; grid 64x4 = 256
  gemm8<2,1><<<256, 512, SH, stream>>>(x2b, WkT, bk, k, D, D, 0,0,0, 1.0f, 64, 4);
  // vT[b] = WvT @ x2[b]^T + bv(per-row): M=D,N=S,K=D; grid 4x8x8 = 256
  gemm8<2,2><<<256, 512, SH, stream>>>(WvT, x2b, bv, vT, S, D, 0, (long)S*D, (long)D*S, 1.0f, 4, 8);
  // q1 = x1 @ Wq + bq: grid 256
  gemm8<2,1><<<256, 512, SH, stream>>>(x1b, WqT, bq, q, D, D, 0,0,0, 1.0f, 64, 4);
  // scores = q k^T / 32 (fp16): M=S,N=S,K=D; grid 8x8x8 = 512
  gemm8<1,0><<<512, 512, SH, stream>>>(q, k, nullptr, Sc, S, D,
                                       (long)S*D, (long)S*D, (long)S*S, 0.03125f, 8, 8);
  // softmax rows, in place -> bf16 probs
  softmax_rows<<<BS,256,0,stream>>>(Sc, S);
  // O = P @ V: A=P[S,S] bf16, Bt=vT[D,S], C=f32 out: M=S,N=D,K=S; grid 8x4x8 = 256
  gemm8<0,0><<<256, 512, SH, stream>>>((short*)Sc, vT, nullptr, d_out, D, S,
                                       (long)S*S, (long)D*S, (long)S*D, 1.0f, 8, 4);
}